// Round 1
// baseline (890.510 us; speedup 1.0000x reference)
//
#include <hip/hip_runtime.h>

#define N_NODES 100000
#define N_HE    30000
#define N_INC   300000

// ---------------------------------------------------------------- CSR build

__global__ void zero_kernel(int* __restrict__ p, int n) {
  int i = blockIdx.x * blockDim.x + threadIdx.x;
  if (i < n) p[i] = 0;
}

__global__ void count_kernel(const int* __restrict__ nidx, const int* __restrict__ hidx,
                             int* __restrict__ node_cnt, int* __restrict__ he_cnt) {
  int i = blockIdx.x * blockDim.x + threadIdx.x;
  if (i < N_INC) {
    atomicAdd(&node_cnt[nidx[i]], 1);
    atomicAdd(&he_cnt[hidx[i]], 1);
  }
}

__global__ void scan1(const int* __restrict__ cnt, int* __restrict__ incl,
                      int* __restrict__ bsums, int n) {
  __shared__ int tmp[1024];
  int tid = threadIdx.x;
  int i = blockIdx.x * 1024 + tid;
  tmp[tid] = (i < n) ? cnt[i] : 0;
  __syncthreads();
  for (int off = 1; off < 1024; off <<= 1) {
    int t = (tid >= off) ? tmp[tid - off] : 0;
    __syncthreads();
    tmp[tid] += t;
    __syncthreads();
  }
  if (i < n) incl[i] = tmp[tid];
  if (tid == 1023) bsums[blockIdx.x] = tmp[1023];
}

__global__ void scan2(int* __restrict__ bsums, int nb) {
  if (threadIdx.x == 0 && blockIdx.x == 0) {
    int run = 0;
    for (int b = 0; b < nb; b++) { int v = bsums[b]; bsums[b] = run; run += v; }
  }
}

__global__ void scan3(const int* __restrict__ cnt, const int* __restrict__ incl,
                      const int* __restrict__ bsums, int* __restrict__ ptr,
                      int* __restrict__ fill, int n) {
  int i = blockIdx.x * 1024 + threadIdx.x;
  if (i < n) {
    int e = incl[i] - cnt[i] + bsums[blockIdx.x];
    ptr[i] = e;
    fill[i] = e;
    if (i == n - 1) ptr[n] = incl[i] + bsums[blockIdx.x];
  }
}

__global__ void fill_kernel(const int* __restrict__ nidx, const int* __restrict__ hidx,
                            int* __restrict__ node_fill, int* __restrict__ he_fill,
                            int* __restrict__ node_hes, int* __restrict__ he_nodes) {
  int i = blockIdx.x * blockDim.x + threadIdx.x;
  if (i < N_INC) {
    int nn = nidx[i], hh = hidx[i];
    int p1 = atomicAdd(&node_fill[nn], 1);
    node_hes[p1] = hh;
    int p2 = atomicAdd(&he_fill[hh], 1);
    he_nodes[p2] = nn;
  }
}

// ---------------------------------------------------------------- GEMM (fp32, BN-folded on input)
// Y[M,N] = (X*scale+shift)[M,K] @ W[K,N]
// 64x64 tile, BK=16, 256 threads, 4x4 per thread.

#define GBM 64
#define GBN 64
#define GBK 16

__global__ __launch_bounds__(256) void gemm_bn(
    const float* __restrict__ X, const float* __restrict__ W,
    const float* __restrict__ scale, const float* __restrict__ shift,
    float* __restrict__ Y, int M, int K, int N) {
  __shared__ float Xs[GBK][GBM];   // transposed [k][m] so a-frag is a float4
  __shared__ float Ws[GBK][GBN];
  const int bm = blockIdx.x * GBM;
  const int bn = blockIdx.y * GBN;
  const int t  = threadIdx.x;
  const int tx = t & 15, ty = t >> 4;
  float acc[4][4] = {};
  for (int kb = 0; kb < K; kb += GBK) {
    // stage X tile: thread -> row m = t/4, k-quad = (t%4)*4
    {
      int m  = t >> 2;
      int kq = (t & 3) << 2;
      int gm = bm + m;
      float4 v = make_float4(0.f, 0.f, 0.f, 0.f);
      if (gm < M) v = *(const float4*)(X + (size_t)gm * K + kb + kq);
      if (scale) {
        int k0 = kb + kq;
        v.x = fmaf(v.x, scale[k0 + 0], shift[k0 + 0]);
        v.y = fmaf(v.y, scale[k0 + 1], shift[k0 + 1]);
        v.z = fmaf(v.z, scale[k0 + 2], shift[k0 + 2]);
        v.w = fmaf(v.w, scale[k0 + 3], shift[k0 + 3]);
      }
      Xs[kq + 0][m] = v.x;
      Xs[kq + 1][m] = v.y;
      Xs[kq + 2][m] = v.z;
      Xs[kq + 3][m] = v.w;
    }
    // stage W tile: thread -> k = t/16, n-quad = (t%16)*4
    {
      int k  = t >> 4;
      int nq = (t & 15) << 2;
      *(float4*)&Ws[k][nq] = *(const float4*)(W + (size_t)(kb + k) * N + bn + nq);
    }
    __syncthreads();
#pragma unroll
    for (int k = 0; k < GBK; k++) {
      const float4 a = *(const float4*)&Xs[k][ty << 2];
      const float4 b = *(const float4*)&Ws[k][tx << 2];
      const float av[4] = {a.x, a.y, a.z, a.w};
      const float bv[4] = {b.x, b.y, b.z, b.w};
#pragma unroll
      for (int i = 0; i < 4; i++)
#pragma unroll
        for (int j = 0; j < 4; j++)
          acc[i][j] = fmaf(av[i], bv[j], acc[i][j]);
    }
    __syncthreads();
  }
#pragma unroll
  for (int i = 0; i < 4; i++) {
    int gm = bm + (ty << 2) + i;
    if (gm < M) {
      float4 o = make_float4(acc[i][0], acc[i][1], acc[i][2], acc[i][3]);
      *(float4*)(Y + (size_t)gm * N + bn + (tx << 2)) = o;
    }
  }
}

// ---------------------------------------------------------------- segment gather-mean
// dst[seg,:] = (1/deg) * sum_{j in [ptr[seg],ptr[seg+1])} src[idx[j],:]  (+bias, relu)
// one (sub-)wave per segment; lane owns a float4 of channels.

__global__ __launch_bounds__(256) void agg_kernel(
    const float* __restrict__ src, const int* __restrict__ ptr, const int* __restrict__ idx,
    const float* __restrict__ bias, float* __restrict__ dst,
    int F, int nSeg, int doRelu) {
  const int nf4   = F >> 2;            // float4s per row (64 or 32)
  const int rpw   = 64 / nf4;          // segments per wave (1 or 2)
  const int gwave = (blockIdx.x * 256 + threadIdx.x) >> 6;
  const int lane  = threadIdx.x & 63;
  const int sub   = lane / nf4;
  const int l     = lane - sub * nf4;
  const int seg   = gwave * rpw + sub;
  if (seg >= nSeg) return;
  const int beg = ptr[seg], end = ptr[seg + 1];
  float4 acc = make_float4(0.f, 0.f, 0.f, 0.f);
  for (int j = beg; j < end; j++) {
    const int s = idx[j];
    const float4 v = *(const float4*)(src + (size_t)s * F + (l << 2));
    acc.x += v.x; acc.y += v.y; acc.z += v.z; acc.w += v.w;
  }
  const float inv = (end > beg) ? 1.0f / (float)(end - beg) : 0.0f;
  acc.x *= inv; acc.y *= inv; acc.z *= inv; acc.w *= inv;
  if (bias) {
    const float4 b = *(const float4*)(bias + (l << 2));
    acc.x += b.x; acc.y += b.y; acc.z += b.z; acc.w += b.w;
  }
  if (doRelu) {
    acc.x = fmaxf(acc.x, 0.f); acc.y = fmaxf(acc.y, 0.f);
    acc.z = fmaxf(acc.z, 0.f); acc.w = fmaxf(acc.w, 0.f);
  }
  *(float4*)(dst + (size_t)seg * F + (l << 2)) = acc;
}

// hyperedge->node pass for F=256 with fused bias+relu+BN-stat partials.
// 4 waves/block, each wave does 16 nodes; lane owns channels [lane*4, lane*4+4).

__global__ __launch_bounds__(256) void node_agg_stats(
    const float* __restrict__ he, const int* __restrict__ nptr,
    const int* __restrict__ nhes, const float* __restrict__ bias,
    float* __restrict__ dst, int nNodes,
    float* __restrict__ gsum, float* __restrict__ gss) {
  const int F = 256;
  const int w = threadIdx.x >> 6;
  const int lane = threadIdx.x & 63;
  const int c0 = lane << 2;
  const float4 b = *(const float4*)(bias + c0);
  float4 s  = make_float4(0.f, 0.f, 0.f, 0.f);
  float4 ss = make_float4(0.f, 0.f, 0.f, 0.f);
  for (int i = 0; i < 16; i++) {
    int n = blockIdx.x * 64 + w * 16 + i;
    if (n >= nNodes) break;   // wave-uniform
    int beg = nptr[n], end = nptr[n + 1];
    float4 acc = make_float4(0.f, 0.f, 0.f, 0.f);
    for (int j = beg; j < end; j++) {
      int e = nhes[j];
      const float4 v = *(const float4*)(he + (size_t)e * F + c0);
      acc.x += v.x; acc.y += v.y; acc.z += v.z; acc.w += v.w;
    }
    float inv = (end > beg) ? 1.0f / (float)(end - beg) : 0.0f;
    float4 o;
    o.x = fmaxf(fmaf(acc.x, inv, b.x), 0.f);
    o.y = fmaxf(fmaf(acc.y, inv, b.y), 0.f);
    o.z = fmaxf(fmaf(acc.z, inv, b.z), 0.f);
    o.w = fmaxf(fmaf(acc.w, inv, b.w), 0.f);
    *(float4*)(dst + (size_t)n * F + c0) = o;
    s.x += o.x; s.y += o.y; s.z += o.z; s.w += o.w;
    ss.x += o.x * o.x; ss.y += o.y * o.y; ss.z += o.z * o.z; ss.w += o.w * o.w;
  }
  __shared__ float ls[4][256], lss[4][256];
  ls[w][c0 + 0] = s.x;  ls[w][c0 + 1] = s.y;  ls[w][c0 + 2] = s.z;  ls[w][c0 + 3] = s.w;
  lss[w][c0 + 0] = ss.x; lss[w][c0 + 1] = ss.y; lss[w][c0 + 2] = ss.z; lss[w][c0 + 3] = ss.w;
  __syncthreads();
  int c = threadIdx.x;
  float a  = ls[0][c] + ls[1][c] + ls[2][c] + ls[3][c];
  float a2 = lss[0][c] + lss[1][c] + lss[2][c] + lss[3][c];
  atomicAdd(gsum + c, a);
  atomicAdd(gss + c, a2);
}

__global__ void bn_finalize(const float* __restrict__ gsum, const float* __restrict__ gss,
                            const float* __restrict__ g, const float* __restrict__ be,
                            float* __restrict__ scale, float* __restrict__ shift, float invN) {
  int c = threadIdx.x;  // 256
  float m = gsum[c] * invN;
  float v = gss[c] * invN - m * m;
  float sc = g[c] * rsqrtf(v + 1e-5f);
  scale[c] = sc;
  shift[c] = be[c] - m * sc;
}

// ---------------------------------------------------------------- launch

extern "C" void kernel_launch(void* const* d_in, const int* in_sizes, int n_in,
                              void* d_out, int out_size, void* d_ws, size_t ws_size,
                              hipStream_t stream) {
  const float* x   = (const float*)d_in[0];
  const int*   edge = (const int*)d_in[1];
  const int*   nidx = edge;                // edge[0] = node indices
  const int*   hidx = edge + N_INC;        // edge[1] = hyperedge indices
  const float* W1  = (const float*)d_in[2];
  const float* b1  = (const float*)d_in[3];
  const float* g1  = (const float*)d_in[4];
  const float* be1 = (const float*)d_in[5];
  const float* W2  = (const float*)d_in[6];
  const float* b2  = (const float*)d_in[7];
  const float* g2  = (const float*)d_in[8];
  const float* be2 = (const float*)d_in[9];
  const float* W3  = (const float*)d_in[10];
  const float* b3  = (const float*)d_in[11];
  float* out = (float*)d_out;

  char* ws = (char*)d_ws;
  size_t off = 0;
  auto alloc = [&](size_t bytes) -> void* {
    void* p = ws + off;
    off = (off + bytes + 255) & ~(size_t)255;
    return p;
  };
  float* A  = (float*)alloc((size_t)N_NODES * 256 * 4);
  float* B  = (float*)alloc((size_t)N_NODES * 256 * 4);
  float* HE = (float*)alloc((size_t)N_HE * 256 * 4);
  size_t zero_begin = off;
  int* he_cnt   = (int*)alloc((size_t)N_HE * 4);
  int* node_cnt = (int*)alloc((size_t)N_NODES * 4);
  float* gsum1 = (float*)alloc(1024);
  float* gss1  = (float*)alloc(1024);
  float* gsum2 = (float*)alloc(1024);
  float* gss2  = (float*)alloc(1024);
  size_t zero_end = off;
  int* he_ptr    = (int*)alloc((size_t)(N_HE + 1) * 4);
  int* node_ptr  = (int*)alloc((size_t)(N_NODES + 1) * 4);
  int* he_fill   = (int*)alloc((size_t)N_HE * 4);
  int* node_fill = (int*)alloc((size_t)N_NODES * 4);
  int* he_nodes  = (int*)alloc((size_t)N_INC * 4);
  int* node_hes  = (int*)alloc((size_t)N_INC * 4);
  int* incl      = (int*)alloc((size_t)N_NODES * 4);   // scan scratch, reused
  int* bsums     = (int*)alloc(512);                   // scan scratch, reused
  float* scale1 = (float*)alloc(1024);
  float* shift1 = (float*)alloc(1024);
  float* scale2 = (float*)alloc(1024);
  float* shift2 = (float*)alloc(1024);

  // ---- CSR build (per launch; ws is poisoned each call) ----
  int zero_ints = (int)((zero_end - zero_begin) / 4);
  zero_kernel<<<(zero_ints + 255) / 256, 256, 0, stream>>>(he_cnt, zero_ints);
  count_kernel<<<(N_INC + 255) / 256, 256, 0, stream>>>(nidx, hidx, node_cnt, he_cnt);
  // hyperedge CSR
  {
    int nb = (N_HE + 1023) / 1024;
    scan1<<<nb, 1024, 0, stream>>>(he_cnt, incl, bsums, N_HE);
    scan2<<<1, 64, 0, stream>>>(bsums, nb);
    scan3<<<nb, 1024, 0, stream>>>(he_cnt, incl, bsums, he_ptr, he_fill, N_HE);
  }
  // node CSR
  {
    int nb = (N_NODES + 1023) / 1024;
    scan1<<<nb, 1024, 0, stream>>>(node_cnt, incl, bsums, N_NODES);
    scan2<<<1, 64, 0, stream>>>(bsums, nb);
    scan3<<<nb, 1024, 0, stream>>>(node_cnt, incl, bsums, node_ptr, node_fill, N_NODES);
  }
  fill_kernel<<<(N_INC + 255) / 256, 256, 0, stream>>>(nidx, hidx, node_fill, he_fill,
                                                       node_hes, he_nodes);

  const int mblocks = (N_NODES + GBM - 1) / GBM;   // 1563
  const float invN = 1.0f / (float)N_NODES;

  // ---- layer 1: Y = x @ W1 ; he-agg ; node-agg(+b1, relu, stats) ----
  {
    dim3 g(mblocks, 256 / GBN);
    gemm_bn<<<g, 256, 0, stream>>>(x, W1, nullptr, nullptr, A, N_NODES, 128, 256);
  }
  agg_kernel<<<(N_HE + 3) / 4, 256, 0, stream>>>(A, he_ptr, he_nodes, nullptr, HE, 256, N_HE, 0);
  node_agg_stats<<<(N_NODES + 63) / 64, 256, 0, stream>>>(HE, node_ptr, node_hes, b1, B,
                                                          N_NODES, gsum1, gss1);
  bn_finalize<<<1, 256, 0, stream>>>(gsum1, gss1, g1, be1, scale1, shift1, invN);

  // ---- layer 2: Y = BN(B) @ W2 ; he-agg ; node-agg(+b2, relu, stats) ----
  {
    dim3 g(mblocks, 256 / GBN);
    gemm_bn<<<g, 256, 0, stream>>>(B, W2, scale1, shift1, A, N_NODES, 256, 256);
  }
  agg_kernel<<<(N_HE + 3) / 4, 256, 0, stream>>>(A, he_ptr, he_nodes, nullptr, HE, 256, N_HE, 0);
  node_agg_stats<<<(N_NODES + 63) / 64, 256, 0, stream>>>(HE, node_ptr, node_hes, b2, B,
                                                          N_NODES, gsum2, gss2);
  bn_finalize<<<1, 256, 0, stream>>>(gsum2, gss2, g2, be2, scale2, shift2, invN);

  // ---- layer 3: Y = BN(B) @ W3 ; he-agg ; node-agg(+b3, relu) -> out ----
  {
    dim3 g(mblocks, 128 / GBN);
    gemm_bn<<<g, 256, 0, stream>>>(B, W3, scale2, shift2, A, N_NODES, 256, 128);
  }
  // F=128: 2 segments per wave
  {
    int waves = (N_HE + 1) / 2;
    agg_kernel<<<(waves + 3) / 4, 256, 0, stream>>>(A, he_ptr, he_nodes, nullptr, HE, 128, N_HE, 0);
  }
  {
    int waves = (N_NODES + 1) / 2;
    agg_kernel<<<(waves + 3) / 4, 256, 0, stream>>>(HE, node_ptr, node_hes, b3, out, 128, N_NODES, 1);
  }
}

// Round 2
// 809.785 us; speedup vs baseline: 1.0997x; 1.0997x over previous
//
#include <hip/hip_runtime.h>

#define N_NODES 100000
#define N_HE    30000
#define N_INC   300000
#define MPAD    100096          // 782 * 128

typedef short  short8  __attribute__((ext_vector_type(8)));
typedef float  floatx4 __attribute__((ext_vector_type(4)));

__device__ inline unsigned short f2bf(float f) {
  unsigned int u = __float_as_uint(f);
  u = (u + 0x7fff + ((u >> 16) & 1)) >> 16;   // round-to-nearest-even
  return (unsigned short)u;
}
__device__ inline unsigned int pack2(float lo, float hi) {
  return (unsigned int)f2bf(lo) | ((unsigned int)f2bf(hi) << 16);
}
__device__ inline void acc8(uint4 rv, float* a) {
  unsigned int u;
  u = rv.x; a[0] += __uint_as_float(u << 16); a[1] += __uint_as_float(u & 0xffff0000u);
  u = rv.y; a[2] += __uint_as_float(u << 16); a[3] += __uint_as_float(u & 0xffff0000u);
  u = rv.z; a[4] += __uint_as_float(u << 16); a[5] += __uint_as_float(u & 0xffff0000u);
  u = rv.w; a[6] += __uint_as_float(u << 16); a[7] += __uint_as_float(u & 0xffff0000u);
}

// ---------------------------------------------------------------- CSR build

__global__ void zero_kernel(int* __restrict__ p, int n) {
  int i = blockIdx.x * blockDim.x + threadIdx.x;
  if (i < n) p[i] = 0;
}

__global__ void count_kernel(const int* __restrict__ nidx, const int* __restrict__ hidx,
                             int* __restrict__ node_cnt, int* __restrict__ he_cnt) {
  int i = blockIdx.x * blockDim.x + threadIdx.x;
  if (i < N_INC) {
    atomicAdd(&node_cnt[nidx[i]], 1);
    atomicAdd(&he_cnt[hidx[i]], 1);
  }
}

__global__ void scan1(const int* __restrict__ cnt, int* __restrict__ incl,
                      int* __restrict__ bsums, int n) {
  __shared__ int tmp[1024];
  int tid = threadIdx.x;
  int i = blockIdx.x * 1024 + tid;
  tmp[tid] = (i < n) ? cnt[i] : 0;
  __syncthreads();
  for (int off = 1; off < 1024; off <<= 1) {
    int t = (tid >= off) ? tmp[tid - off] : 0;
    __syncthreads();
    tmp[tid] += t;
    __syncthreads();
  }
  if (i < n) incl[i] = tmp[tid];
  if (tid == 1023) bsums[blockIdx.x] = tmp[1023];
}

__global__ void scan2(int* __restrict__ bsums, int nb) {
  if (threadIdx.x == 0 && blockIdx.x == 0) {
    int run = 0;
    for (int b = 0; b < nb; b++) { int v = bsums[b]; bsums[b] = run; run += v; }
  }
}

__global__ void scan3(const int* __restrict__ cnt, const int* __restrict__ incl,
                      const int* __restrict__ bsums, int* __restrict__ ptr,
                      int* __restrict__ fill, int n) {
  int i = blockIdx.x * 1024 + threadIdx.x;
  if (i < n) {
    int e = incl[i] - cnt[i] + bsums[blockIdx.x];
    ptr[i] = e;
    fill[i] = e;
    if (i == n - 1) ptr[n] = incl[i] + bsums[blockIdx.x];
  }
}

__global__ void fill_kernel(const int* __restrict__ nidx, const int* __restrict__ hidx,
                            int* __restrict__ node_fill, int* __restrict__ he_fill,
                            int* __restrict__ node_hes, int* __restrict__ he_nodes) {
  int i = blockIdx.x * blockDim.x + threadIdx.x;
  if (i < N_INC) {
    int nn = nidx[i], hh = hidx[i];
    int p1 = atomicAdd(&node_fill[nn], 1);
    node_hes[p1] = hh;
    int p2 = atomicAdd(&he_fill[hh], 1);
    he_nodes[p2] = nn;
  }
}

// ---------------------------------------------------------------- converters / weight fold

// x f32 [N_NODES,128] -> bf16 (pad rows left poisoned; never consumed)
__global__ void convert_x(const float* __restrict__ x, unsigned short* __restrict__ xb) {
  int i = blockIdx.x * 256 + threadIdx.x;      // 8 elems per thread
  if (i >= N_NODES * 16) return;
  const float4* p = (const float4*)x + (size_t)i * 2;
  float4 a = p[0], b = p[1];
  uint4 o;
  o.x = pack2(a.x, a.y); o.y = pack2(a.z, a.w);
  o.z = pack2(b.x, b.y); o.w = pack2(b.z, b.w);
  *(uint4*)(xb + (size_t)i * 8) = o;
}

// WT[n][k] = bf16(W[k][n]*scale[k]);  cvec[n] = sum_k shift[k]*W[k][n]
__global__ void fold_w(const float* __restrict__ W, const float* __restrict__ scale,
                       const float* __restrict__ shift, unsigned short* __restrict__ WT,
                       float* __restrict__ cvec, int K, int N) {
  int n = threadIdx.x;
  if (n >= N) return;
  float c = 0.f;
  for (int k = 0; k < K; k++) {
    float w = W[(size_t)k * N + n];
    float s = scale ? scale[k] : 1.f;
    float t = shift ? shift[k] : 0.f;
    WT[(size_t)n * K + k] = f2bf(w * s);
    c += t * w;
  }
  cvec[n] = c;
}

__global__ void bn_finalize(const float* __restrict__ gsum, const float* __restrict__ gss,
                            const float* __restrict__ g, const float* __restrict__ be,
                            float* __restrict__ scale, float* __restrict__ shift, float invN) {
  int c = threadIdx.x;  // 256
  float m = gsum[c] * invN;
  float v = gss[c] * invN - m * m;
  float sc = g[c] * rsqrtf(v + 1e-5f);
  scale[c] = sc;
  shift[c] = be[c] - m * sc;
}

// ---------------------------------------------------------------- bf16 MFMA GEMM (m97 pattern)
// C[M,N] = A[M,K] @ BT[N,K]^T, all bf16, fp32 accumulate. 128x128 tile, BK=32.
// M must be a multiple of 128 (buffers padded); K mult of 32; N mult of 128.

__global__ __launch_bounds__(256) void gemm_mfma(
    const unsigned short* __restrict__ A, const unsigned short* __restrict__ BT,
    unsigned short* __restrict__ C, int K, int N) {
  __shared__ unsigned short As[128 * 32];
  __shared__ unsigned short Bs[128 * 32];
  const int tid  = threadIdx.x;
  const int w    = tid >> 6, lane = tid & 63;
  const int wm   = w & 1,  wn   = w >> 1;
  const int bm   = blockIdx.x * 128, bn = blockIdx.y * 128;
  const int quad = lane >> 4, r16 = lane & 15;

  floatx4 acc[4][4] = {};

  const int srow = (lane >> 2);          // 0..15 within 16-row chunk
  const int scol = (lane & 3) * 8;       // bf16 elems, 16B granules

  for (int kb = 0; kb < K; kb += 32) {
#pragma unroll
    for (int i = 0; i < 2; i++) {
      const int row = (w * 2 + i) * 16 + srow;
      const unsigned short* ga = A  + (size_t)(bm + row) * K + kb + scol;
      const unsigned short* gb = BT + (size_t)(bn + row) * K + kb + scol;
      __builtin_amdgcn_global_load_lds(
          (const __attribute__((address_space(1))) void*)ga,
          (__attribute__((address_space(3))) void*)(&As[(w * 2 + i) * 512]), 16, 0, 0);
      __builtin_amdgcn_global_load_lds(
          (const __attribute__((address_space(1))) void*)gb,
          (__attribute__((address_space(3))) void*)(&Bs[(w * 2 + i) * 512]), 16, 0, 0);
    }
    __syncthreads();
    short8 af[4], bfr[4];
#pragma unroll
    for (int t = 0; t < 4; t++) {
      af[t]  = *(const short8*)&As[(wm * 64 + t * 16 + r16) * 32 + quad * 8];
      bfr[t] = *(const short8*)&Bs[(wn * 64 + t * 16 + r16) * 32 + quad * 8];
    }
#pragma unroll
    for (int mi = 0; mi < 4; mi++)
#pragma unroll
      for (int ni = 0; ni < 4; ni++)
        acc[mi][ni] = __builtin_amdgcn_mfma_f32_16x16x32_bf16(af[mi], bfr[ni], acc[mi][ni], 0, 0, 0);
    __syncthreads();
  }
  // C/D layout: col = lane&15, row = quad*4 + reg  (m89/m91-verified)
#pragma unroll
  for (int mi = 0; mi < 4; mi++)
#pragma unroll
    for (int ni = 0; ni < 4; ni++)
#pragma unroll
      for (int rr = 0; rr < 4; rr++) {
        int gm = bm + wm * 64 + mi * 16 + quad * 4 + rr;
        int gn = bn + wn * 64 + ni * 16 + r16;
        C[(size_t)gm * N + gn] = f2bf(acc[mi][ni][rr]);
      }
}

// ---------------------------------------------------------------- aggregations (bf16 in/out)

// dst[seg] = mean of src rows (bf16). F/8 lanes per segment; shift = log2(F/8).
__global__ __launch_bounds__(256) void agg_he(
    const unsigned short* __restrict__ src, const int* __restrict__ ptr,
    const int* __restrict__ idx, unsigned short* __restrict__ dst,
    int F, int shift, int nSeg) {
  int seg = blockIdx.x * (256 >> shift) + (threadIdx.x >> shift);
  if (seg >= nSeg) return;
  int l = threadIdx.x & ((1 << shift) - 1);
  int c0 = l * 8;
  int beg = ptr[seg], end = ptr[seg + 1];
  float a[8] = {};
  for (int j = beg; j < end; j++) {
    int s = idx[j];
    uint4 rv = *(const uint4*)(src + (size_t)s * F + c0);
    acc8(rv, a);
  }
  float inv = (end > beg) ? 1.0f / (float)(end - beg) : 0.0f;
  uint4 o;
  o.x = pack2(a[0] * inv, a[1] * inv);
  o.y = pack2(a[2] * inv, a[3] * inv);
  o.z = pack2(a[4] * inv, a[5] * inv);
  o.w = pack2(a[6] * inv, a[7] * inv);
  *(uint4*)(dst + (size_t)seg * F + c0) = o;
}

// hyperedge->node, F=256, fused bias(+cvec if deg>0) + relu + BN stats. bf16 out.
__global__ __launch_bounds__(256) void node_agg_bn(
    const unsigned short* __restrict__ he, const int* __restrict__ nptr,
    const int* __restrict__ nhes, const float* __restrict__ b,
    const float* __restrict__ cvec, unsigned short* __restrict__ dst,
    float* __restrict__ gsum, float* __restrict__ gss) {
  const int F = 256;
  const int half = threadIdx.x >> 5, l = threadIdx.x & 31, c0 = l * 8;
  float bb[8], cc[8];
#pragma unroll
  for (int j = 0; j < 8; j++) { bb[j] = b[c0 + j]; cc[j] = cvec[c0 + j]; }
  float s[8] = {}, ss[8] = {};
  for (int i = 0; i < 16; i++) {
    int n = blockIdx.x * 128 + i * 8 + half;
    if (n >= N_NODES) continue;
    int beg = nptr[n], end = nptr[n + 1];
    float a[8] = {};
    for (int j = beg; j < end; j++) {
      int e = nhes[j];
      uint4 rv = *(const uint4*)(he + (size_t)e * F + c0);
      acc8(rv, a);
    }
    float inv = (end > beg) ? 1.0f / (float)(end - beg) : 0.0f;
    float cmul = (end > beg) ? 1.0f : 0.0f;   // deg-0 node: +b only (no folded t@W)
    float o[8];
#pragma unroll
    for (int j = 0; j < 8; j++) {
      o[j] = fmaxf(fmaf(a[j], inv, bb[j] + cmul * cc[j]), 0.f);
      s[j] += o[j]; ss[j] += o[j] * o[j];
    }
    uint4 ov;
    ov.x = pack2(o[0], o[1]); ov.y = pack2(o[2], o[3]);
    ov.z = pack2(o[4], o[5]); ov.w = pack2(o[6], o[7]);
    *(uint4*)(dst + (size_t)n * F + c0) = ov;
  }
  __shared__ float Ls[8][256];
  __shared__ float Lss[8][256];
#pragma unroll
  for (int j = 0; j < 8; j++) { Ls[half][c0 + j] = s[j]; Lss[half][c0 + j] = ss[j]; }
  __syncthreads();
  int c = threadIdx.x;
  float a1 = 0.f, a2 = 0.f;
#pragma unroll
  for (int h = 0; h < 8; h++) { a1 += Ls[h][c]; a2 += Lss[h][c]; }
  atomicAdd(gsum + c, a1);
  atomicAdd(gss + c, a2);
}

// final hyperedge->node, F=128, +b3(+c3 if deg>0), relu, f32 out.
__global__ __launch_bounds__(256) void agg_out(
    const unsigned short* __restrict__ he, const int* __restrict__ nptr,
    const int* __restrict__ nhes, const float* __restrict__ b,
    const float* __restrict__ cvec, float* __restrict__ out) {
  const int F = 128;
  int g = threadIdx.x >> 4, l = threadIdx.x & 15, c0 = l * 8;
  int n = blockIdx.x * 16 + g;
  if (n >= N_NODES) return;
  int beg = nptr[n], end = nptr[n + 1];
  float a[8] = {};
  for (int j = beg; j < end; j++) {
    int e = nhes[j];
    uint4 rv = *(const uint4*)(he + (size_t)e * F + c0);
    acc8(rv, a);
  }
  float inv = (end > beg) ? 1.0f / (float)(end - beg) : 0.0f;
  float cmul = (end > beg) ? 1.0f : 0.0f;
  float4 o0, o1;
  o0.x = fmaxf(fmaf(a[0], inv, b[c0 + 0] + cmul * cvec[c0 + 0]), 0.f);
  o0.y = fmaxf(fmaf(a[1], inv, b[c0 + 1] + cmul * cvec[c0 + 1]), 0.f);
  o0.z = fmaxf(fmaf(a[2], inv, b[c0 + 2] + cmul * cvec[c0 + 2]), 0.f);
  o0.w = fmaxf(fmaf(a[3], inv, b[c0 + 3] + cmul * cvec[c0 + 3]), 0.f);
  o1.x = fmaxf(fmaf(a[4], inv, b[c0 + 4] + cmul * cvec[c0 + 4]), 0.f);
  o1.y = fmaxf(fmaf(a[5], inv, b[c0 + 5] + cmul * cvec[c0 + 5]), 0.f);
  o1.z = fmaxf(fmaf(a[6], inv, b[c0 + 6] + cmul * cvec[c0 + 6]), 0.f);
  o1.w = fmaxf(fmaf(a[7], inv, b[c0 + 7] + cmul * cvec[c0 + 7]), 0.f);
  float* dp = out + (size_t)n * F + c0;
  *(float4*)dp = o0;
  *(float4*)(dp + 4) = o1;
}

// ---------------------------------------------------------------- launch

extern "C" void kernel_launch(void* const* d_in, const int* in_sizes, int n_in,
                              void* d_out, int out_size, void* d_ws, size_t ws_size,
                              hipStream_t stream) {
  const float* x    = (const float*)d_in[0];
  const int*   edge = (const int*)d_in[1];
  const int*   nidx = edge;
  const int*   hidx = edge + N_INC;
  const float* W1  = (const float*)d_in[2];
  const float* b1  = (const float*)d_in[3];
  const float* g1  = (const float*)d_in[4];
  const float* be1 = (const float*)d_in[5];
  const float* W2  = (const float*)d_in[6];
  const float* b2  = (const float*)d_in[7];
  const float* g2  = (const float*)d_in[8];
  const float* be2 = (const float*)d_in[9];
  const float* W3  = (const float*)d_in[10];
  const float* b3  = (const float*)d_in[11];
  float* out = (float*)d_out;

  char* ws = (char*)d_ws;
  size_t off = 0;
  auto alloc = [&](size_t bytes) -> void* {
    void* p = ws + off;
    off = (off + bytes + 255) & ~(size_t)255;
    return p;
  };
  unsigned short* Xb  = (unsigned short*)alloc((size_t)MPAD * 128 * 2);
  unsigned short* Ab  = (unsigned short*)alloc((size_t)MPAD * 256 * 2);
  unsigned short* Bb  = (unsigned short*)alloc((size_t)MPAD * 256 * 2);
  unsigned short* HEb = (unsigned short*)alloc((size_t)N_HE * 256 * 2);
  unsigned short* W1T = (unsigned short*)alloc((size_t)256 * 128 * 2);
  unsigned short* W2T = (unsigned short*)alloc((size_t)256 * 256 * 2);
  unsigned short* W3T = (unsigned short*)alloc((size_t)128 * 256 * 2);
  size_t zero_begin = off;
  int* he_cnt   = (int*)alloc((size_t)N_HE * 4);
  int* node_cnt = (int*)alloc((size_t)N_NODES * 4);
  float* gsum1 = (float*)alloc(1024);
  float* gss1  = (float*)alloc(1024);
  float* gsum2 = (float*)alloc(1024);
  float* gss2  = (float*)alloc(1024);
  size_t zero_end = off;
  int* he_ptr    = (int*)alloc((size_t)(N_HE + 1) * 4);
  int* node_ptr  = (int*)alloc((size_t)(N_NODES + 1) * 4);
  int* he_fill   = (int*)alloc((size_t)N_HE * 4);
  int* node_fill = (int*)alloc((size_t)N_NODES * 4);
  int* he_nodes  = (int*)alloc((size_t)N_INC * 4);
  int* node_hes  = (int*)alloc((size_t)N_INC * 4);
  int* incl      = (int*)alloc((size_t)N_NODES * 4);
  int* bsums     = (int*)alloc(512);
  float* scale1 = (float*)alloc(1024);
  float* shift1 = (float*)alloc(1024);
  float* scale2 = (float*)alloc(1024);
  float* shift2 = (float*)alloc(1024);
  float* c1 = (float*)alloc(1024);
  float* c2 = (float*)alloc(1024);
  float* c3 = (float*)alloc(1024);

  // ---- CSR build ----
  int zero_ints = (int)((zero_end - zero_begin) / 4);
  zero_kernel<<<(zero_ints + 255) / 256, 256, 0, stream>>>(he_cnt, zero_ints);
  count_kernel<<<(N_INC + 255) / 256, 256, 0, stream>>>(nidx, hidx, node_cnt, he_cnt);
  {
    int nb = (N_HE + 1023) / 1024;
    scan1<<<nb, 1024, 0, stream>>>(he_cnt, incl, bsums, N_HE);
    scan2<<<1, 64, 0, stream>>>(bsums, nb);
    scan3<<<nb, 1024, 0, stream>>>(he_cnt, incl, bsums, he_ptr, he_fill, N_HE);
  }
  {
    int nb = (N_NODES + 1023) / 1024;
    scan1<<<nb, 1024, 0, stream>>>(node_cnt, incl, bsums, N_NODES);
    scan2<<<1, 64, 0, stream>>>(bsums, nb);
    scan3<<<nb, 1024, 0, stream>>>(node_cnt, incl, bsums, node_ptr, node_fill, N_NODES);
  }
  fill_kernel<<<(N_INC + 255) / 256, 256, 0, stream>>>(nidx, hidx, node_fill, he_fill,
                                                       node_hes, he_nodes);

  // ---- precompute ----
  convert_x<<<(N_NODES * 16 + 255) / 256, 256, 0, stream>>>(x, Xb);
  fold_w<<<1, 256, 0, stream>>>(W1, nullptr, nullptr, W1T, c1, 128, 256);

  const int MB = MPAD / 128;            // 782
  const float invN = 1.0f / (float)N_NODES;

  // ---- layer 1 ----
  { dim3 g(MB, 2); gemm_mfma<<<g, 256, 0, stream>>>(Xb, W1T, Ab, 128, 256); }
  agg_he<<<(N_HE + 7) / 8, 256, 0, stream>>>(Ab, he_ptr, he_nodes, HEb, 256, 5, N_HE);
  node_agg_bn<<<(N_NODES + 127) / 128, 256, 0, stream>>>(HEb, node_ptr, node_hes, b1, c1,
                                                         Bb, gsum1, gss1);
  bn_finalize<<<1, 256, 0, stream>>>(gsum1, gss1, g1, be1, scale1, shift1, invN);

  // ---- layer 2 ----
  fold_w<<<1, 256, 0, stream>>>(W2, scale1, shift1, W2T, c2, 256, 256);
  { dim3 g(MB, 2); gemm_mfma<<<g, 256, 0, stream>>>(Bb, W2T, Ab, 256, 256); }
  agg_he<<<(N_HE + 7) / 8, 256, 0, stream>>>(Ab, he_ptr, he_nodes, HEb, 256, 5, N_HE);
  node_agg_bn<<<(N_NODES + 127) / 128, 256, 0, stream>>>(HEb, node_ptr, node_hes, b2, c2,
                                                         Bb, gsum2, gss2);
  bn_finalize<<<1, 256, 0, stream>>>(gsum2, gss2, g2, be2, scale2, shift2, invN);

  // ---- layer 3 ----
  fold_w<<<1, 256, 0, stream>>>(W3, scale2, shift2, W3T, c3, 256, 128);
  { dim3 g(MB, 1); gemm_mfma<<<g, 256, 0, stream>>>(Bb, W3T, Ab, 256, 128); }
  agg_he<<<(N_HE + 15) / 16, 256, 0, stream>>>(Ab, he_ptr, he_nodes, HEb, 128, 4, N_HE);
  agg_out<<<(N_NODES + 15) / 16, 256, 0, stream>>>(HEb, node_ptr, node_hes, b3, c3, out);
}

// Round 3
// 523.247 us; speedup vs baseline: 1.7019x; 1.5476x over previous
//
#include <hip/hip_runtime.h>

#define N_NODES 100000
#define N_HE    30000
#define N_INC   300000
#define MPAD    100096          // 782 * 128

typedef short  short8  __attribute__((ext_vector_type(8)));
typedef float  floatx4 __attribute__((ext_vector_type(4)));

__device__ inline unsigned short f2bf(float f) {
  unsigned int u = __float_as_uint(f);
  u = (u + 0x7fff + ((u >> 16) & 1)) >> 16;   // round-to-nearest-even
  return (unsigned short)u;
}
__device__ inline unsigned int pack2(float lo, float hi) {
  return (unsigned int)f2bf(lo) | ((unsigned int)f2bf(hi) << 16);
}
__device__ inline void acc8(uint4 rv, float* a) {
  unsigned int u;
  u = rv.x; a[0] += __uint_as_float(u << 16); a[1] += __uint_as_float(u & 0xffff0000u);
  u = rv.y; a[2] += __uint_as_float(u << 16); a[3] += __uint_as_float(u & 0xffff0000u);
  u = rv.z; a[4] += __uint_as_float(u << 16); a[5] += __uint_as_float(u & 0xffff0000u);
  u = rv.w; a[6] += __uint_as_float(u << 16); a[7] += __uint_as_float(u & 0xffff0000u);
}

// ---------------------------------------------------------------- CSR build

__global__ void zero_kernel(int* __restrict__ p, int n) {
  int i = blockIdx.x * blockDim.x + threadIdx.x;
  if (i < n) p[i] = 0;
}

__global__ void count_kernel(const int* __restrict__ nidx, const int* __restrict__ hidx,
                             int* __restrict__ node_cnt, int* __restrict__ he_cnt) {
  int i = blockIdx.x * blockDim.x + threadIdx.x;
  if (i < N_INC) {
    atomicAdd(&node_cnt[nidx[i]], 1);
    atomicAdd(&he_cnt[hidx[i]], 1);
  }
}

__global__ void scan1(const int* __restrict__ cnt, int* __restrict__ incl,
                      int* __restrict__ bsums, int n) {
  __shared__ int tmp[1024];
  int tid = threadIdx.x;
  int i = blockIdx.x * 1024 + tid;
  tmp[tid] = (i < n) ? cnt[i] : 0;
  __syncthreads();
  for (int off = 1; off < 1024; off <<= 1) {
    int t = (tid >= off) ? tmp[tid - off] : 0;
    __syncthreads();
    tmp[tid] += t;
    __syncthreads();
  }
  if (i < n) incl[i] = tmp[tid];
  if (tid == 1023) bsums[blockIdx.x] = tmp[1023];
}

__global__ void scan2(int* __restrict__ bsums, int nb) {
  if (threadIdx.x == 0 && blockIdx.x == 0) {
    int run = 0;
    for (int b = 0; b < nb; b++) { int v = bsums[b]; bsums[b] = run; run += v; }
  }
}

__global__ void scan3(const int* __restrict__ cnt, const int* __restrict__ incl,
                      const int* __restrict__ bsums, int* __restrict__ ptr,
                      int* __restrict__ fill, int n) {
  int i = blockIdx.x * 1024 + threadIdx.x;
  if (i < n) {
    int e = incl[i] - cnt[i] + bsums[blockIdx.x];
    ptr[i] = e;
    fill[i] = e;
    if (i == n - 1) ptr[n] = incl[i] + bsums[blockIdx.x];
  }
}

__global__ void fill_kernel(const int* __restrict__ nidx, const int* __restrict__ hidx,
                            int* __restrict__ node_fill, int* __restrict__ he_fill,
                            int* __restrict__ node_hes, int* __restrict__ he_nodes) {
  int i = blockIdx.x * blockDim.x + threadIdx.x;
  if (i < N_INC) {
    int nn = nidx[i], hh = hidx[i];
    int p1 = atomicAdd(&node_fill[nn], 1);
    node_hes[p1] = hh;
    int p2 = atomicAdd(&he_fill[hh], 1);
    he_nodes[p2] = nn;
  }
}

// ---------------------------------------------------------------- converters / weight fold

// x f32 [N_NODES,128] -> bf16 (pad rows never consumed)
__global__ void convert_x(const float* __restrict__ x, unsigned short* __restrict__ xb) {
  int i = blockIdx.x * 256 + threadIdx.x;      // 8 elems per thread
  if (i >= N_NODES * 16) return;
  const float4* p = (const float4*)x + (size_t)i * 2;
  float4 a = p[0], b = p[1];
  uint4 o;
  o.x = pack2(a.x, a.y); o.y = pack2(a.z, a.w);
  o.z = pack2(b.x, b.y); o.w = pack2(b.z, b.w);
  *(uint4*)(xb + (size_t)i * 8) = o;
}

// WT[n][k] = bf16(W[k][n]*scale[k]);  cvec[n] += partial sum_k shift[k]*W[k][n]
// grid (K/16, ceil(N/256)), block 256. cvec must be pre-zeroed.
__global__ __launch_bounds__(256) void fold_w(
    const float* __restrict__ W, const float* __restrict__ scale,
    const float* __restrict__ shift, unsigned short* __restrict__ WT,
    float* __restrict__ cvec, int K, int N) {
  int n = blockIdx.y * 256 + threadIdx.x;
  if (n >= N) return;
  int k0 = blockIdx.x * 16;
  float c = 0.f;
  unsigned short loc[16];
#pragma unroll
  for (int i = 0; i < 16; i++) {
    int k = k0 + i;
    float w = W[(size_t)k * N + n];
    float s = scale ? scale[k] : 1.f;
    float t = shift ? shift[k] : 0.f;
    loc[i] = f2bf(w * s);
    c += t * w;
  }
  *(uint4*)(WT + (size_t)n * K + k0)     = *(const uint4*)&loc[0];
  *(uint4*)(WT + (size_t)n * K + k0 + 8) = *(const uint4*)&loc[8];
  atomicAdd(cvec + n, c);
}

__global__ void bn_finalize(const float* __restrict__ gsum, const float* __restrict__ gss,
                            const float* __restrict__ g, const float* __restrict__ be,
                            float* __restrict__ scale, float* __restrict__ shift, float invN) {
  int c = threadIdx.x;  // 256
  float m = gsum[c] * invN;
  float v = gss[c] * invN - m * m;
  float sc = g[c] * rsqrtf(v + 1e-5f);
  scale[c] = sc;
  shift[c] = be[c] - m * sc;
}

// ---------------------------------------------------------------- bf16 MFMA GEMM (m97 pattern)
// C[M,N] = A[M,K] @ BT[N,K]^T, all bf16, fp32 accumulate. 128x128 tile, BK=32.

__global__ __launch_bounds__(256) void gemm_mfma(
    const unsigned short* __restrict__ A, const unsigned short* __restrict__ BT,
    unsigned short* __restrict__ C, int K, int N) {
  __shared__ unsigned short As[128 * 32];
  __shared__ unsigned short Bs[128 * 32];
  const int tid  = threadIdx.x;
  const int w    = tid >> 6, lane = tid & 63;
  const int wm   = w & 1,  wn   = w >> 1;
  const int bm   = blockIdx.x * 128, bn = blockIdx.y * 128;
  const int quad = lane >> 4, r16 = lane & 15;

  floatx4 acc[4][4] = {};

  const int srow = (lane >> 2);          // 0..15 within 16-row chunk
  const int scol = (lane & 3) * 8;       // bf16 elems, 16B granules

  for (int kb = 0; kb < K; kb += 32) {
#pragma unroll
    for (int i = 0; i < 2; i++) {
      const int row = (w * 2 + i) * 16 + srow;
      const unsigned short* ga = A  + (size_t)(bm + row) * K + kb + scol;
      const unsigned short* gb = BT + (size_t)(bn + row) * K + kb + scol;
      __builtin_amdgcn_global_load_lds(
          (const __attribute__((address_space(1))) void*)ga,
          (__attribute__((address_space(3))) void*)(&As[(w * 2 + i) * 512]), 16, 0, 0);
      __builtin_amdgcn_global_load_lds(
          (const __attribute__((address_space(1))) void*)gb,
          (__attribute__((address_space(3))) void*)(&Bs[(w * 2 + i) * 512]), 16, 0, 0);
    }
    __syncthreads();
    short8 af[4], bfr[4];
#pragma unroll
    for (int t = 0; t < 4; t++) {
      af[t]  = *(const short8*)&As[(wm * 64 + t * 16 + r16) * 32 + quad * 8];
      bfr[t] = *(const short8*)&Bs[(wn * 64 + t * 16 + r16) * 32 + quad * 8];
    }
#pragma unroll
    for (int mi = 0; mi < 4; mi++)
#pragma unroll
      for (int ni = 0; ni < 4; ni++)
        acc[mi][ni] = __builtin_amdgcn_mfma_f32_16x16x32_bf16(af[mi], bfr[ni], acc[mi][ni], 0, 0, 0);
    __syncthreads();
  }
  // C/D layout: col = lane&15, row = quad*4 + reg
#pragma unroll
  for (int mi = 0; mi < 4; mi++)
#pragma unroll
    for (int ni = 0; ni < 4; ni++)
#pragma unroll
      for (int rr = 0; rr < 4; rr++) {
        int gm = bm + wm * 64 + mi * 16 + quad * 4 + rr;
        int gn = bn + wn * 64 + ni * 16 + r16;
        C[(size_t)gm * N + gn] = f2bf(acc[mi][ni][rr]);
      }
}

// ---------------------------------------------------------------- aggregations (bf16 in/out)

__global__ __launch_bounds__(256) void agg_he(
    const unsigned short* __restrict__ src, const int* __restrict__ ptr,
    const int* __restrict__ idx, unsigned short* __restrict__ dst,
    int F, int shift, int nSeg) {
  int seg = blockIdx.x * (256 >> shift) + (threadIdx.x >> shift);
  if (seg >= nSeg) return;
  int l = threadIdx.x & ((1 << shift) - 1);
  int c0 = l * 8;
  int beg = ptr[seg], end = ptr[seg + 1];
  float a[8] = {};
  for (int j = beg; j < end; j++) {
    int s = idx[j];
    uint4 rv = *(const uint4*)(src + (size_t)s * F + c0);
    acc8(rv, a);
  }
  float inv = (end > beg) ? 1.0f / (float)(end - beg) : 0.0f;
  uint4 o;
  o.x = pack2(a[0] * inv, a[1] * inv);
  o.y = pack2(a[2] * inv, a[3] * inv);
  o.z = pack2(a[4] * inv, a[5] * inv);
  o.w = pack2(a[6] * inv, a[7] * inv);
  *(uint4*)(dst + (size_t)seg * F + c0) = o;
}

// hyperedge->node, F=256, fused bias(+cvec if deg>0) + relu + BN stats. bf16 out.
__global__ __launch_bounds__(256) void node_agg_bn(
    const unsigned short* __restrict__ he, const int* __restrict__ nptr,
    const int* __restrict__ nhes, const float* __restrict__ b,
    const float* __restrict__ cvec, unsigned short* __restrict__ dst,
    float* __restrict__ gsum, float* __restrict__ gss) {
  const int F = 256;
  const int half = threadIdx.x >> 5, l = threadIdx.x & 31, c0 = l * 8;
  float bb[8], cc[8];
#pragma unroll
  for (int j = 0; j < 8; j++) { bb[j] = b[c0 + j]; cc[j] = cvec[c0 + j]; }
  float s[8] = {}, ss[8] = {};
  for (int i = 0; i < 16; i++) {
    int n = blockIdx.x * 128 + i * 8 + half;
    if (n >= N_NODES) continue;
    int beg = nptr[n], end = nptr[n + 1];
    float a[8] = {};
    for (int j = beg; j < end; j++) {
      int e = nhes[j];
      uint4 rv = *(const uint4*)(he + (size_t)e * F + c0);
      acc8(rv, a);
    }
    float inv = (end > beg) ? 1.0f / (float)(end - beg) : 0.0f;
    float cmul = (end > beg) ? 1.0f : 0.0f;   // deg-0 node: +b only
    float o[8];
#pragma unroll
    for (int j = 0; j < 8; j++) {
      o[j] = fmaxf(fmaf(a[j], inv, bb[j] + cmul * cc[j]), 0.f);
      s[j] += o[j]; ss[j] += o[j] * o[j];
    }
    uint4 ov;
    ov.x = pack2(o[0], o[1]); ov.y = pack2(o[2], o[3]);
    ov.z = pack2(o[4], o[5]); ov.w = pack2(o[6], o[7]);
    *(uint4*)(dst + (size_t)n * F + c0) = ov;
  }
  __shared__ float Ls[8][256];
  __shared__ float Lss[8][256];
#pragma unroll
  for (int j = 0; j < 8; j++) { Ls[half][c0 + j] = s[j]; Lss[half][c0 + j] = ss[j]; }
  __syncthreads();
  int c = threadIdx.x;
  float a1 = 0.f, a2 = 0.f;
#pragma unroll
  for (int h = 0; h < 8; h++) { a1 += Ls[h][c]; a2 += Lss[h][c]; }
  atomicAdd(gsum + c, a1);
  atomicAdd(gss + c, a2);
}

// final hyperedge->node, F=128, +b3(+c3 if deg>0), relu, f32 out.
__global__ __launch_bounds__(256) void agg_out(
    const unsigned short* __restrict__ he, const int* __restrict__ nptr,
    const int* __restrict__ nhes, const float* __restrict__ b,
    const float* __restrict__ cvec, float* __restrict__ out) {
  const int F = 128;
  int g = threadIdx.x >> 4, l = threadIdx.x & 15, c0 = l * 8;
  int n = blockIdx.x * 16 + g;
  if (n >= N_NODES) return;
  int beg = nptr[n], end = nptr[n + 1];
  float a[8] = {};
  for (int j = beg; j < end; j++) {
    int e = nhes[j];
    uint4 rv = *(const uint4*)(he + (size_t)e * F + c0);
    acc8(rv, a);
  }
  float inv = (end > beg) ? 1.0f / (float)(end - beg) : 0.0f;
  float cmul = (end > beg) ? 1.0f : 0.0f;
  float4 o0, o1;
  o0.x = fmaxf(fmaf(a[0], inv, b[c0 + 0] + cmul * cvec[c0 + 0]), 0.f);
  o0.y = fmaxf(fmaf(a[1], inv, b[c0 + 1] + cmul * cvec[c0 + 1]), 0.f);
  o0.z = fmaxf(fmaf(a[2], inv, b[c0 + 2] + cmul * cvec[c0 + 2]), 0.f);
  o0.w = fmaxf(fmaf(a[3], inv, b[c0 + 3] + cmul * cvec[c0 + 3]), 0.f);
  o1.x = fmaxf(fmaf(a[4], inv, b[c0 + 4] + cmul * cvec[c0 + 4]), 0.f);
  o1.y = fmaxf(fmaf(a[5], inv, b[c0 + 5] + cmul * cvec[c0 + 5]), 0.f);
  o1.z = fmaxf(fmaf(a[6], inv, b[c0 + 6] + cmul * cvec[c0 + 6]), 0.f);
  o1.w = fmaxf(fmaf(a[7], inv, b[c0 + 7] + cmul * cvec[c0 + 7]), 0.f);
  float* dp = out + (size_t)n * F + c0;
  *(float4*)dp = o0;
  *(float4*)(dp + 4) = o1;
}

// ---------------------------------------------------------------- launch

extern "C" void kernel_launch(void* const* d_in, const int* in_sizes, int n_in,
                              void* d_out, int out_size, void* d_ws, size_t ws_size,
                              hipStream_t stream) {
  const float* x    = (const float*)d_in[0];
  const int*   edge = (const int*)d_in[1];
  const int*   nidx = edge;
  const int*   hidx = edge + N_INC;
  const float* W1  = (const float*)d_in[2];
  const float* b1  = (const float*)d_in[3];
  const float* g1  = (const float*)d_in[4];
  const float* be1 = (const float*)d_in[5];
  const float* W2  = (const float*)d_in[6];
  const float* b2  = (const float*)d_in[7];
  const float* g2  = (const float*)d_in[8];
  const float* be2 = (const float*)d_in[9];
  const float* W3  = (const float*)d_in[10];
  const float* b3  = (const float*)d_in[11];
  float* out = (float*)d_out;

  char* ws = (char*)d_ws;
  size_t off = 0;
  auto alloc = [&](size_t bytes) -> void* {
    void* p = ws + off;
    off = (off + bytes + 255) & ~(size_t)255;
    return p;
  };
  unsigned short* Xb  = (unsigned short*)alloc((size_t)MPAD * 128 * 2);
  unsigned short* Ab  = (unsigned short*)alloc((size_t)MPAD * 256 * 2);
  unsigned short* Bb  = (unsigned short*)alloc((size_t)MPAD * 256 * 2);
  unsigned short* HEb = (unsigned short*)alloc((size_t)N_HE * 256 * 2);
  unsigned short* W1T = (unsigned short*)alloc((size_t)256 * 128 * 2);
  unsigned short* W2T = (unsigned short*)alloc((size_t)256 * 256 * 2);
  unsigned short* W3T = (unsigned short*)alloc((size_t)128 * 256 * 2);
  size_t zero_begin = off;
  int* he_cnt   = (int*)alloc((size_t)N_HE * 4);
  int* node_cnt = (int*)alloc((size_t)N_NODES * 4);
  float* gsum1 = (float*)alloc(1024);
  float* gss1  = (float*)alloc(1024);
  float* gsum2 = (float*)alloc(1024);
  float* gss2  = (float*)alloc(1024);
  float* c1 = (float*)alloc(1024);
  float* c2 = (float*)alloc(1024);
  float* c3 = (float*)alloc(1024);
  size_t zero_end = off;
  int* he_ptr    = (int*)alloc((size_t)(N_HE + 1) * 4);
  int* node_ptr  = (int*)alloc((size_t)(N_NODES + 1) * 4);
  int* he_fill   = (int*)alloc((size_t)N_HE * 4);
  int* node_fill = (int*)alloc((size_t)N_NODES * 4);
  int* he_nodes  = (int*)alloc((size_t)N_INC * 4);
  int* node_hes  = (int*)alloc((size_t)N_INC * 4);
  int* incl      = (int*)alloc((size_t)N_NODES * 4);
  int* bsums     = (int*)alloc(512);
  float* scale1 = (float*)alloc(1024);
  float* shift1 = (float*)alloc(1024);
  float* scale2 = (float*)alloc(1024);
  float* shift2 = (float*)alloc(1024);

  // ---- CSR build ----
  int zero_ints = (int)((zero_end - zero_begin) / 4);
  zero_kernel<<<(zero_ints + 255) / 256, 256, 0, stream>>>(he_cnt, zero_ints);
  count_kernel<<<(N_INC + 255) / 256, 256, 0, stream>>>(nidx, hidx, node_cnt, he_cnt);
  {
    int nb = (N_HE + 1023) / 1024;
    scan1<<<nb, 1024, 0, stream>>>(he_cnt, incl, bsums, N_HE);
    scan2<<<1, 64, 0, stream>>>(bsums, nb);
    scan3<<<nb, 1024, 0, stream>>>(he_cnt, incl, bsums, he_ptr, he_fill, N_HE);
  }
  {
    int nb = (N_NODES + 1023) / 1024;
    scan1<<<nb, 1024, 0, stream>>>(node_cnt, incl, bsums, N_NODES);
    scan2<<<1, 64, 0, stream>>>(bsums, nb);
    scan3<<<nb, 1024, 0, stream>>>(node_cnt, incl, bsums, node_ptr, node_fill, N_NODES);
  }
  fill_kernel<<<(N_INC + 255) / 256, 256, 0, stream>>>(nidx, hidx, node_fill, he_fill,
                                                       node_hes, he_nodes);

  // ---- precompute ----
  convert_x<<<(N_NODES * 16 + 255) / 256, 256, 0, stream>>>(x, Xb);
  { dim3 g(128 / 16, 1); fold_w<<<g, 256, 0, stream>>>(W1, nullptr, nullptr, W1T, c1, 128, 256); }

  const int MB = MPAD / 128;            // 782
  const float invN = 1.0f / (float)N_NODES;

  // ---- layer 1 ----
  { dim3 g(MB, 2); gemm_mfma<<<g, 256, 0, stream>>>(Xb, W1T, Ab, 128, 256); }
  agg_he<<<(N_HE + 7) / 8, 256, 0, stream>>>(Ab, he_ptr, he_nodes, HEb, 256, 5, N_HE);
  node_agg_bn<<<(N_NODES + 127) / 128, 256, 0, stream>>>(HEb, node_ptr, node_hes, b1, c1,
                                                         Bb, gsum1, gss1);
  bn_finalize<<<1, 256, 0, stream>>>(gsum1, gss1, g1, be1, scale1, shift1, invN);

  // ---- layer 2 ----
  { dim3 g(256 / 16, 1); fold_w<<<g, 256, 0, stream>>>(W2, scale1, shift1, W2T, c2, 256, 256); }
  { dim3 g(MB, 2); gemm_mfma<<<g, 256, 0, stream>>>(Bb, W2T, Ab, 256, 256); }
  agg_he<<<(N_HE + 7) / 8, 256, 0, stream>>>(Ab, he_ptr, he_nodes, HEb, 256, 5, N_HE);
  node_agg_bn<<<(N_NODES + 127) / 128, 256, 0, stream>>>(HEb, node_ptr, node_hes, b2, c2,
                                                         Bb, gsum2, gss2);
  bn_finalize<<<1, 256, 0, stream>>>(gsum2, gss2, g2, be2, scale2, shift2, invN);

  // ---- layer 3 ----
  { dim3 g(256 / 16, 1); fold_w<<<g, 256, 0, stream>>>(W3, scale2, shift2, W3T, c3, 256, 128); }
  { dim3 g(MB, 1); gemm_mfma<<<g, 256, 0, stream>>>(Bb, W3T, Ab, 256, 128); }
  agg_he<<<(N_HE + 15) / 16, 256, 0, stream>>>(Ab, he_ptr, he_nodes, HEb, 128, 4, N_HE);
  agg_out<<<(N_NODES + 15) / 16, 256, 0, stream>>>(HEb, node_ptr, node_hes, b3, c3, out);
}